// Round 9
// baseline (180.345 us; speedup 1.0000x reference)
//
#include <hip/hip_runtime.h>
#include <stdint.h>

// ---------------------------------------------------------------------------
// TopK: scores = (embs @ scorer)/sum(scorer) + mask; top-k rows; out = rows^T
// Ordering matches numpy/OpenBLAS sgemv_t fp32 bits exactly (verified
// R3/R5/R6/R8, absmax=0): per row, 8 mod-8 fma chains (chain c sums elements
// c, c+8, ... ascending), reduced as ((L0+L4)+(L1+L5)) + ((L2+L6)+(L3+L7)),
// realized as 8 threads/row + shfl_xor pair-sums (bitwise-commutative adds).
// R9: ENTIRE pipeline fused into one persistent kernel (512 blocks = 2/CU,
// co-residency guaranteed by LDS: ~51KB/block) with 3 device-scope spin
// barriers. R8's five small kernels + five dependent-launch gaps were ~2/3
// of the 60us. Phases: P1 scores+LDS-hist(+pre-aggregated global-atomic
// flush; max 512 same-address adds) | bar | P2 per-block redundant
// suffix-scan -> bucket B | P3 grid-stride compact | bar | P4 rank | bar |
// P5 gather+transpose. kInit zeroes hist+hdr (graph-replay safe).
// ---------------------------------------------------------------------------

#define NBINS 8192   // 13-bit radix: sign + exp(8) + mantissa(4)
#define BIN_SHIFT 19
#define CAP 4096     // candidates: k + boundary bin (~600) << CAP
#define GRID 512     // 2 blocks/CU -> all resident (barrier-safe)

__device__ __forceinline__ uint32_t f2key(float f) {
  uint32_t b = __float_as_uint(f);
  return (b & 0x80000000u) ? ~b : (b | 0x80000000u);
}

// non-cooperative grid barrier: monotonically increasing counter, target = j*G
__device__ __forceinline__ void gbar(uint32_t* cnt, uint32_t target) {
  __syncthreads();
  if (threadIdx.x == 0) {
    __threadfence();  // publish prior global stores (agent scope)
    __hip_atomic_fetch_add(cnt, 1u, __ATOMIC_ACQ_REL, __HIP_MEMORY_SCOPE_AGENT);
    while (__hip_atomic_load(cnt, __ATOMIC_ACQUIRE, __HIP_MEMORY_SCOPE_AGENT) < target)
      __builtin_amdgcn_s_sleep(2);
  }
  __syncthreads();
}

__global__ __launch_bounds__(256) void kInit(uint32_t* __restrict__ hdr,
                                             uint32_t* __restrict__ hist) {
  int i = blockIdx.x * 256 + threadIdx.x;
  if (i < NBINS) hist[i] = 0u;
  if (i < 16) hdr[i] = 0u;  // [0]=B [2]=cand counter [8]=barrier counter
}

__global__ __launch_bounds__(256, 2) void kMega(
    const float* __restrict__ embs, const float* __restrict__ mask,
    const float* __restrict__ scorer, uint32_t* __restrict__ keys,
    uint32_t* __restrict__ hdr, uint32_t* __restrict__ hist,
    uint32_t* __restrict__ ckey, uint32_t* __restrict__ cidx,
    uint32_t* __restrict__ oidx, float* __restrict__ out, int N, int k) {
  __shared__ uint32_t hbuf[NBINS];   // P1: local hist | P4: lk[CAP]+li[CAP]
  __shared__ float tile[32 * 132];   // P1 staging | P5 gather tile (16*132)
  __shared__ float sw[256];
  __shared__ float Ssh;
  __shared__ uint32_t sB;
  __shared__ uint32_t wtot[4], wsuf[4];
  __shared__ uint32_t wcnt[4], wbase[4], blkbase;
  __shared__ uint32_t sidx[16];

  const int t = threadIdx.x;
  const int bid = blockIdx.x;
  const int G = gridDim.x;
  const int lane = t & 63, wave = t >> 6;
  uint32_t* barcnt = hdr + 8;

  // ---- P0: zero local hist; load scorer; S = (float)sum_f64(scorer) ----
  for (int i = t; i < NBINS; i += 256) hbuf[i] = 0u;
  sw[t] = scorer[t];  // F == 256
  __syncthreads();
  if (t < 64) {
    double s = 0.0;
    for (int j = t; j < 256; j += 64) s += (double)sw[j];
#pragma unroll
    for (int off = 32; off >= 1; off >>= 1) s += __shfl_xor(s, off, 64);
    if (t == 0) Ssh = (float)s;
  }
  __syncthreads();
  float S = Ssh;

  // ---- P1: scores (bit-exact R8 body), keys, LDS hist ----
  const float4* e4 = (const float4*)embs;
  int r = t >> 3, c = t & 7;
  int ntile = (N + 31) >> 5;
  for (int ti = bid; ti < ntile; ti += G) {
    int r0 = ti * 32;
    float acc = 0.f;
#pragma unroll
    for (int ch = 0; ch < 2; ++ch) {
      __syncthreads();  // tile reuse (prev iter/chunk readers done)
#pragma unroll
      for (int m = 0; m < 4; ++m) {    // 1024 f4 = 32 rows x 32 f4
        int flat = m * 256 + t;
        int rr = flat >> 5, cc4 = flat & 31;
        int row = r0 + rr;
        float4 v = make_float4(0.f, 0.f, 0.f, 0.f);
        if (row < N) v = e4[(size_t)row * 64 + ch * 32 + cc4];  // 512B segs
        float* dst = &tile[rr * 132 + cc4 * 4];
        dst[0] = v.x; dst[1] = v.y; dst[2] = v.z; dst[3] = v.w;
      }
      __syncthreads();
#pragma unroll
      for (int sl = 0; sl < 16; ++sl)  // ascending k within mod-8 chain
        acc = fmaf(tile[r * 132 + c + 8 * sl], sw[ch * 128 + c + 8 * sl], acc);
    }
    // exact OpenBLAS bracket via commutative pair-sums:
    float m1 = acc + __shfl_xor(acc, 4, 64);
    float p1 = m1 + __shfl_xor(m1, 1, 64);
    float dot = p1 + __shfl_xor(p1, 2, 64);
    int row = r0 + r;
    if (c == 0 && row < N) {
      float score = dot / S + mask[row];
      uint32_t key = f2key(score);
      keys[row] = key;
      atomicAdd(&hbuf[key >> BIN_SHIFT], 1u);  // LDS atomic, tiny contention
    }
  }
  __syncthreads();
  // flush pre-aggregated local hist (<=512 same-address adds per bin total)
  for (int i = t; i < NBINS; i += 256) {
    uint32_t v = hbuf[i];
    if (v) atomicAdd(&hist[i], v);
  }
  gbar(barcnt, G);  // ---- barrier 1: hist + keys complete ----

  // ---- P2: every block redundantly computes bucket B from hist ----
  {
    uint32_t rb[32];
    uint32_t p = 0;
    const uint4* h4 = (const uint4*)hist + t * 8;  // 32 bins/thread
#pragma unroll
    for (int i = 0; i < 8; ++i) {
      uint4 a = h4[i];
      rb[4*i+0] = a.x; rb[4*i+1] = a.y; rb[4*i+2] = a.z; rb[4*i+3] = a.w;
      p += a.x + a.y + a.z + a.w;
    }
    // wave-internal inclusive suffix scan
    uint32_t x = p;
#pragma unroll
    for (int off = 1; off < 64; off <<= 1) {
      uint32_t v = __shfl_down(x, off, 64);
      if (lane + off < 64) x += v;
    }
    if (lane == 0) wtot[wave] = x;
    __syncthreads();
    if (t < 4) {
      uint32_t y = wtot[t];
#pragma unroll
      for (int off = 1; off < 4; off <<= 1) {
        uint32_t v = __shfl_down(y, off, 64);
        if (t + off < 4) y += v;
      }
      wsuf[t] = y - wtot[t];  // sum of waves after t
    }
    __syncthreads();
    uint32_t St = x + wsuf[wave];  // count(bin >= 32t)
    uint32_t above = St - p;       // count(bin >= 32(t+1))
    if (above < (uint32_t)k && St >= (uint32_t)k) {  // unique thread
      uint32_t cum = above;
#pragma unroll
      for (int jj = 31; jj >= 0; --jj) {
        if (cum + rb[jj] >= (uint32_t)k) { sB = (uint32_t)(t * 32 + jj); break; }
        cum += rb[jj];
      }
    }
    __syncthreads();
  }
  uint32_t B = sB;

  // ---- P3: grid-stride compact (bin >= B) ----
  int nchunk = (N + 255) >> 8;
  for (int cc = bid; cc < nchunk; cc += G) {
    int i = cc * 256 + t;
    bool pred = false;
    uint32_t key = 0;
    if (i < N) { key = keys[i]; pred = (key >> BIN_SHIFT) >= B; }
    unsigned long long ball = __ballot(pred);
    uint32_t prefix = (uint32_t)__popcll(ball & ((1ull << lane) - 1ull));
    if (lane == 0) wcnt[wave] = (uint32_t)__popcll(ball);
    __syncthreads();
    if (t == 0) {
      uint32_t tot = wcnt[0] + wcnt[1] + wcnt[2] + wcnt[3];
      blkbase = tot ? atomicAdd(&hdr[2], tot) : 0u;
      wbase[0] = 0;
      wbase[1] = wcnt[0];
      wbase[2] = wcnt[0] + wcnt[1];
      wbase[3] = wcnt[0] + wcnt[1] + wcnt[2];
    }
    __syncthreads();
    if (pred) {
      uint32_t pos = blkbase + wbase[wave] + prefix;
      if (pos < CAP) { ckey[pos] = key; cidx[pos] = (uint32_t)i; }
    }
  }
  gbar(barcnt, 2u * G);  // ---- barrier 2: candidates complete ----

  // ---- P4: exact rank (key desc, idx asc); 16 cands/block ----
  {
    uint32_t C = hdr[2];
    if (C > CAP) C = CAP;
    uint32_t* lk = hbuf;        // reuse: CAP words
    uint32_t* li = hbuf + CAP;  // CAP words
    uint32_t nrb = (C + 15u) >> 4;
    if ((uint32_t)bid < nrb) {
      for (uint32_t j = t; j < C; j += 256u) { lk[j] = ckey[j]; li[j] = cidx[j]; }
      __syncthreads();
      uint32_t g0 = (uint32_t)bid * 16u + (uint32_t)wave * 4u;
      uint32_t mk[4], mi[4], cnt[4];
#pragma unroll
      for (int q = 0; q < 4; ++q) {
        uint32_t g = g0 + q;
        bool valid = g < C;
        mk[q] = valid ? lk[g] : 0u;
        mi[q] = valid ? li[g] : 0xFFFFFFFFu;
        cnt[q] = 0u;
      }
      for (uint32_t j = lane; j < C; j += 64u) {
        uint32_t kj = lk[j], ij = li[j];
#pragma unroll
        for (int q = 0; q < 4; ++q)
          cnt[q] += (kj > mk[q] || (kj == mk[q] && ij < mi[q])) ? 1u : 0u;
      }
#pragma unroll
      for (int q = 0; q < 4; ++q) {
#pragma unroll
        for (int off = 32; off >= 1; off >>= 1) cnt[q] += __shfl_xor(cnt[q], off, 64);
      }
      if (lane == 0) {
#pragma unroll
        for (int q = 0; q < 4; ++q) {
          uint32_t g = g0 + q;
          if (g < C && cnt[q] < (uint32_t)k) oidx[cnt[q]] = mi[q];
        }
      }
    }
  }
  gbar(barcnt, 3u * G);  // ---- barrier 3: oidx complete ----

  // ---- P5: gather + transpose; unit = 16 ranks x 128 feats ----
  int units = (((k + 15) >> 4) << 1);
  for (int u = bid; u < units; u += G) {
    int r0 = (u >> 1) * 16;
    int fb = (u & 1) * 128;
    __syncthreads();  // tile/sidx reuse across units
    if (t < 16) sidx[t] = (r0 + t < k) ? oidx[r0 + t] : 0u;
    __syncthreads();
#pragma unroll
    for (int m = 0; m < 2; ++m) {  // 512 f4 = 16 rows x 32 f4
      int flat = m * 256 + t;
      int rr = flat >> 5, cc4 = flat & 31;
      float4 v = e4[(size_t)sidx[rr] * 64 + (fb >> 2) + cc4];
      float* dst = &tile[rr * 132 + cc4 * 4];
      dst[0] = v.x; dst[1] = v.y; dst[2] = v.z; dst[3] = v.w;
    }
    __syncthreads();
    int fl = t >> 1, rq = t & 1;
    float v[8];
#pragma unroll
    for (int i2 = 0; i2 < 8; ++i2) v[i2] = tile[(rq * 8 + i2) * 132 + fl];
    size_t obase = (size_t)(fb + fl) * k + r0 + rq * 8;
    if (((k & 3) == 0) && (r0 + rq * 8 + 7 < k)) {
      *(float4*)(out + obase) = make_float4(v[0], v[1], v[2], v[3]);
      *(float4*)(out + obase + 4) = make_float4(v[4], v[5], v[6], v[7]);
    } else {
#pragma unroll
      for (int i2 = 0; i2 < 8; ++i2)
        if (r0 + rq * 8 + i2 < k) out[obase + i2] = v[i2];
    }
  }
}

extern "C" void kernel_launch(void* const* d_in, const int* in_sizes, int n_in,
                              void* d_out, int out_size, void* d_ws, size_t ws_size,
                              hipStream_t stream) {
  const float* embs = (const float*)d_in[0];
  const float* mask = (const float*)d_in[1];
  const float* scorer = (const float*)d_in[2];
  int F = in_sizes[2];      // 256
  int N = in_sizes[0] / F;  // 100000
  int k = out_size / F;     // 2000

  // keys live in d_out (N*4 = 400KB << 8MB); P5 overwrites all of d_out.
  uint32_t* keys = (uint32_t*)d_out;

  char* ws = (char*)d_ws;
  uint32_t* hdr = (uint32_t*)ws;                     // 1KB (incl barrier ctr)
  uint32_t* hist = (uint32_t*)(ws + 1024);           // 32KB
  uint32_t* ckey = (uint32_t*)(ws + 1024 + NBINS * 4);  // 16KB
  uint32_t* cidx = ckey + CAP;                       // 16KB
  uint32_t* oidx = cidx + CAP;                       // 8KB

  kInit<<<NBINS / 256, 256, 0, stream>>>(hdr, hist);
  kMega<<<GRID, 256, 0, stream>>>(embs, mask, scorer, keys, hdr, hist,
                                  ckey, cidx, oidx, (float*)d_out, N, k);
}

// Round 10
// 95.440 us; speedup vs baseline: 1.8896x; 1.8896x over previous
//
#include <hip/hip_runtime.h>
#include <stdint.h>

// ---------------------------------------------------------------------------
// TopK: scores = (embs @ scorer)/sum(scorer) + mask; top-k rows; out = rows^T
// Ordering matches numpy/OpenBLAS sgemv_t fp32 bits exactly (verified
// R3/R5/R6/R8, absmax=0): per row, 8 mod-8 fma chains (chain c sums elements
// c, c+8, ... ascending), reduced as ((L0+L4)+(L1+L5)) + ((L2+L6)+(L3+L7)),
// realized as 8 threads/row + shfl_xor pair-sums (bitwise-commutative adds).
// R10 = R8 structure minus launch overhead. R9 lesson: wide spin barriers +
// atomic hist flush = cross-XCD same-line RMW storm (~40-300ns each) -> 3x
// regression. Here the only cross-block wait is EIGHT RMWs on one flag line.
//   k1  : scores (R8 verified body) + block0 zeroes hdr.
//   kSel: 391 blocks. bid<8 build partial hists (LDS, plain-store) and
//         release-add a flag; all blocks spin (read-mostly line, s_sleep(8)),
//         then redundantly reduce+suffix-scan partials (R9-P2 verified
//         logic) -> bucket B, and compact their own 256-key slice (R8 k3
//         verified body; 391 same-addr RMWs on hdr[2] -- R8-calibrated OK).
//   k4  : exact rank-by-count (R8 verified). k5: gather+transpose (R8).
// d_out: keys @ [0,400KB); partials @ [1.024MB,+256KB); k5 overwrites all.
// ws: hdr(1KB) ckey(16KB) cidx(16KB) oidx(8KB).
// ---------------------------------------------------------------------------

#define NBINS 8192   // 13-bit radix: sign + exp(8) + mantissa(4)
#define BIN_SHIFT 19
#define CAP 4096     // candidates: k + boundary bin (~600) << CAP
#define HPARTS 8

__device__ __forceinline__ uint32_t f2key(float f) {
  uint32_t b = __float_as_uint(f);
  return (b & 0x80000000u) ? ~b : (b | 0x80000000u);
}

// ---- kernel 1: 32 rows/block, 8 threads/row (one mod-8 chain each) --------
__global__ __launch_bounds__(256) void k1_scores(
    const float* __restrict__ embs, const float* __restrict__ mask,
    const float* __restrict__ scorer,
    uint32_t* __restrict__ keys, uint32_t* __restrict__ hdr, int N) {
  __shared__ float tile[32 * 132];
  __shared__ float sw[256];
  __shared__ float Ssh;
  int t = threadIdx.x;
  int r0 = blockIdx.x * 32;
  if (blockIdx.x == 0 && t < 16) hdr[t] = 0u;  // [2]=cand ctr, [8]=flag
  sw[t] = scorer[t];  // F == 256
  __syncthreads();
  if (t < 64) {
    double s = 0.0;
    for (int j = t; j < 256; j += 64) s += (double)sw[j];
#pragma unroll
    for (int off = 32; off >= 1; off >>= 1) s += __shfl_xor(s, off, 64);
    if (t == 0) Ssh = (float)s;  // f64 sum: order-independent at f32 grain
  }
  __syncthreads();
  float S = Ssh;
  int r = t >> 3, c = t & 7;
  float acc = 0.f;
  const float4* e4 = (const float4*)embs;
#pragma unroll
  for (int ch = 0; ch < 2; ++ch) {
    if (ch) __syncthreads();  // previous chunk's LDS reads complete
#pragma unroll
    for (int m = 0; m < 4; ++m) {      // 4*256 = 1024 f4 = 32 rows x 32 f4
      int flat = m * 256 + t;
      int rr = flat >> 5;              // 0..31
      int cc4 = flat & 31;             // 0..31
      int row = r0 + rr;
      float4 v = make_float4(0.f, 0.f, 0.f, 0.f);
      if (row < N) v = e4[(size_t)row * 64 + ch * 32 + cc4];  // 512B segs
      float* dst = &tile[rr * 132 + cc4 * 4];
      dst[0] = v.x; dst[1] = v.y; dst[2] = v.z; dst[3] = v.w;
    }
    __syncthreads();
#pragma unroll
    for (int sl = 0; sl < 16; ++sl) {  // ascending k within the chain
      acc = fmaf(tile[r * 132 + c + 8 * sl], sw[ch * 128 + c + 8 * sl], acc);
    }
  }
  // exact OpenBLAS bracket via commutative pair-sums (lanes stay in-row):
  float m1 = acc + __shfl_xor(acc, 4, 64);  // L_c + L_{c+4}
  float p1 = m1 + __shfl_xor(m1, 1, 64);    // (m0+m1) / (m2+m3)
  float dot = p1 + __shfl_xor(p1, 2, 64);   // ((m0+m1)+(m2+m3))
  int row = r0 + r;
  if (c == 0 && row < N) {
    float score = dot / S + mask[row];
    keys[row] = f2key(score);
  }
}

// ---- kernel Sel: partial hists (8 workers) | flag | scan -> B | compact ----
__global__ __launch_bounds__(256) void kSel(
    const uint32_t* __restrict__ keys, uint32_t* __restrict__ partials,
    uint32_t* __restrict__ hdr, uint32_t* __restrict__ ckey,
    uint32_t* __restrict__ cidx, int N, int k) {
  __shared__ uint32_t h[2][NBINS];  // 64 KB (workers only)
  __shared__ uint32_t wtot[4], wsuf[4];
  __shared__ uint32_t sB;
  __shared__ uint32_t wcnt[4], wbase[4], blkbase;
  int t = threadIdx.x, bid = blockIdx.x;
  int lane = t & 63, wave = t >> 6;

  // --- phase A: 8 worker blocks build partial hists (plain stores) ---
  if (bid < HPARTS) {
    for (int i = t; i < 2 * NBINS; i += 256) ((uint32_t*)h)[i] = 0u;
    __syncthreads();
    int per = (N + HPARTS - 1) / HPARTS;
    int lo = bid * per;
    int hi = lo + per; if (hi > N) hi = N;
    int sub = (t >> 7) & 1;
    int n4 = (hi - lo) >> 2;
    const uint4* q4 = (const uint4*)(keys + lo);
    for (int i = t; i < n4; i += 256) {
      uint4 v = q4[i];
      atomicAdd(&h[sub][v.x >> BIN_SHIFT], 1u);
      atomicAdd(&h[sub][v.y >> BIN_SHIFT], 1u);
      atomicAdd(&h[sub][v.z >> BIN_SHIFT], 1u);
      atomicAdd(&h[sub][v.w >> BIN_SHIFT], 1u);
    }
    for (int i = lo + (n4 << 2) + t; i < hi; i += 256)
      atomicAdd(&h[sub][keys[i] >> BIN_SHIFT], 1u);
    __syncthreads();
    uint32_t* dst = partials + (size_t)bid * NBINS;
    for (int i = t; i < NBINS; i += 256) dst[i] = h[0][i] + h[1][i];
    __syncthreads();
    if (t == 0) {
      __threadfence();  // publish partials (agent scope)
      __hip_atomic_fetch_add(&hdr[8], 1u, __ATOMIC_ACQ_REL, __HIP_MEMORY_SCOPE_AGENT);
    }
  }
  // --- narrow wait: only 8 RMWs ever touch this line (R9 lesson) ---
  if (t == 0) {
    while (__hip_atomic_load(&hdr[8], __ATOMIC_ACQUIRE, __HIP_MEMORY_SCOPE_AGENT) < HPARTS)
      __builtin_amdgcn_s_sleep(8);
  }
  __syncthreads();

  // --- phase B: redundant reduce of 8 partials + suffix scan (R9-P2) ---
  uint32_t rb[32];
#pragma unroll
  for (int j = 0; j < 32; ++j) rb[j] = 0u;
#pragma unroll
  for (int pp = 0; pp < HPARTS; ++pp) {
    const uint4* q = (const uint4*)(partials + (size_t)pp * NBINS) + t * 8;
#pragma unroll
    for (int i = 0; i < 8; ++i) {
      uint4 a = q[i];
      rb[4*i+0] += a.x; rb[4*i+1] += a.y; rb[4*i+2] += a.z; rb[4*i+3] += a.w;
    }
  }
  uint32_t p = 0;
#pragma unroll
  for (int j = 0; j < 32; ++j) p += rb[j];
  uint32_t x = p;  // wave-internal inclusive suffix scan
#pragma unroll
  for (int off = 1; off < 64; off <<= 1) {
    uint32_t v = __shfl_down(x, off, 64);
    if (lane + off < 64) x += v;
  }
  if (lane == 0) wtot[wave] = x;
  __syncthreads();
  if (t < 4) {
    uint32_t y = wtot[t];
#pragma unroll
    for (int off = 1; off < 4; off <<= 1) {
      uint32_t v = __shfl_down(y, off, 64);
      if (t + off < 4) y += v;
    }
    wsuf[t] = y - wtot[t];  // sum of waves after t
  }
  __syncthreads();
  uint32_t St = x + wsuf[wave];  // count(bin >= 32t)
  uint32_t above = St - p;       // count(bin >= 32(t+1))
  if (above < (uint32_t)k && St >= (uint32_t)k) {  // unique thread
    uint32_t cum = above;
#pragma unroll
    for (int jj = 31; jj >= 0; --jj) {
      if (cum + rb[jj] >= (uint32_t)k) { sB = (uint32_t)(t * 32 + jj); break; }
      cum += rb[jj];
    }
  }
  __syncthreads();
  uint32_t B = sB;

  // --- phase C: compact this block's 256-key slice (R8 k3 body) ---
  int i = bid * 256 + t;
  bool pred = false;
  uint32_t key = 0;
  if (i < N) {
    key = keys[i];
    pred = (key >> BIN_SHIFT) >= B;
  }
  unsigned long long ball = __ballot(pred);
  uint32_t prefix = (uint32_t)__popcll(ball & ((1ull << lane) - 1ull));
  if (lane == 0) wcnt[wave] = (uint32_t)__popcll(ball);
  __syncthreads();
  if (t == 0) {
    uint32_t tot = wcnt[0] + wcnt[1] + wcnt[2] + wcnt[3];
    blkbase = tot ? atomicAdd(&hdr[2], tot) : 0u;
    wbase[0] = 0;
    wbase[1] = wcnt[0];
    wbase[2] = wcnt[0] + wcnt[1];
    wbase[3] = wcnt[0] + wcnt[1] + wcnt[2];
  }
  __syncthreads();
  if (pred) {
    uint32_t pos = blkbase + wbase[wave] + prefix;
    if (pos < CAP) { ckey[pos] = key; cidx[pos] = (uint32_t)i; }
  }
}

// ---- kernel 4: exact rank, 4 candidates/wave, 16/block --------------------
__global__ __launch_bounds__(256) void k4_rank(
    const uint32_t* __restrict__ ckey, const uint32_t* __restrict__ cidx,
    const uint32_t* __restrict__ hdr, uint32_t* __restrict__ oidx, int k) {
  __shared__ uint32_t lk[CAP];
  __shared__ uint32_t li[CAP];
  uint32_t C = hdr[2];
  if (C > CAP) C = CAP;
  uint32_t base = blockIdx.x * 16u;
  if (base >= C) return;
  for (uint32_t j = threadIdx.x; j < C; j += 256u) {
    lk[j] = ckey[j];
    li[j] = cidx[j];
  }
  __syncthreads();
  int wave = threadIdx.x >> 6, lane = threadIdx.x & 63;
  uint32_t g0 = base + wave * 4u;
  uint32_t mk[4], mi[4], cnt[4];
#pragma unroll
  for (int q = 0; q < 4; ++q) {
    uint32_t g = g0 + q;
    bool valid = g < C;
    mk[q] = valid ? lk[g] : 0u;
    mi[q] = valid ? li[g] : 0xFFFFFFFFu;
    cnt[q] = 0u;
  }
  for (uint32_t j = lane; j < C; j += 64u) {
    uint32_t kj = lk[j], ij = li[j];
#pragma unroll
    for (int q = 0; q < 4; ++q)
      cnt[q] += (kj > mk[q] || (kj == mk[q] && ij < mi[q])) ? 1u : 0u;
  }
#pragma unroll
  for (int q = 0; q < 4; ++q) {
#pragma unroll
    for (int off = 32; off >= 1; off >>= 1) cnt[q] += __shfl_xor(cnt[q], off, 64);
  }
  if (lane == 0) {
#pragma unroll
    for (int q = 0; q < 4; ++q) {
      uint32_t g = g0 + q;
      if (g < C && cnt[q] < (uint32_t)k) oidx[cnt[q]] = mi[q];
    }
  }
}

// ---- kernel 5: gather + transpose; 16 ranks x 128 feats per block ----------
__global__ __launch_bounds__(256) void k5_gather(
    const float* __restrict__ embs, const uint32_t* __restrict__ oidx,
    float* __restrict__ out, int k) {
  __shared__ float tile[16 * 132];
  __shared__ uint32_t sidx[16];
  int t = threadIdx.x;
  int r0 = blockIdx.x * 16;
  int fb = blockIdx.y * 128;
  if (t < 16) sidx[t] = (r0 + t < k) ? oidx[r0 + t] : 0u;
  __syncthreads();
  const float4* e4 = (const float4*)embs;
#pragma unroll
  for (int m = 0; m < 2; ++m) {      // 2*256 = 512 f4 = 16 rows x 32 f4
    int flat = m * 256 + t;
    int rr = flat >> 5;
    int cc4 = flat & 31;
    float4 v = e4[(size_t)sidx[rr] * 64 + (fb >> 2) + cc4];
    float* dst = &tile[rr * 132 + cc4 * 4];
    dst[0] = v.x; dst[1] = v.y; dst[2] = v.z; dst[3] = v.w;
  }
  __syncthreads();
  int fl = t >> 1;   // 0..127 local feature
  int rq = t & 1;    // which 8-rank group
  float v[8];
#pragma unroll
  for (int i = 0; i < 8; ++i) v[i] = tile[(rq * 8 + i) * 132 + fl];
  size_t obase = (size_t)(fb + fl) * k + r0 + rq * 8;
  if (((k & 3) == 0) && (r0 + rq * 8 + 7 < k)) {
    *(float4*)(out + obase) = make_float4(v[0], v[1], v[2], v[3]);
    *(float4*)(out + obase + 4) = make_float4(v[4], v[5], v[6], v[7]);
  } else {
#pragma unroll
    for (int i = 0; i < 8; ++i)
      if (r0 + rq * 8 + i < k) out[obase + i] = v[i];
  }
}

extern "C" void kernel_launch(void* const* d_in, const int* in_sizes, int n_in,
                              void* d_out, int out_size, void* d_ws, size_t ws_size,
                              hipStream_t stream) {
  const float* embs = (const float*)d_in[0];
  const float* mask = (const float*)d_in[1];
  const float* scorer = (const float*)d_in[2];
  int F = in_sizes[2];      // 256
  int N = in_sizes[0] / F;  // 100000
  int k = out_size / F;     // 2000

  // d_out scratch layout (overwritten by k5 at the end):
  //   keys     @ [0, N*4)                 = 400 KB
  //   partials @ [out_size/2 * 4, +256KB)
  uint32_t* keys = (uint32_t*)d_out;
  uint32_t* partials = (uint32_t*)d_out + (out_size / 2);

  char* ws = (char*)d_ws;
  uint32_t* hdr = (uint32_t*)ws;                 // 1KB: [2]=C ctr [8]=flag
  uint32_t* ckey = (uint32_t*)(ws + 1024);       // 16KB
  uint32_t* cidx = ckey + CAP;                   // 16KB
  uint32_t* oidx = cidx + CAP;                   // 8KB

  int nsel = (N + 255) / 256;                    // 391 >= HPARTS
  k1_scores<<<(N + 31) / 32, 256, 0, stream>>>(embs, mask, scorer, keys, hdr, N);
  kSel<<<nsel, 256, 0, stream>>>(keys, partials, hdr, ckey, cidx, N, k);
  k4_rank<<<(CAP + 15) / 16, 256, 0, stream>>>(ckey, cidx, hdr, oidx, k);
  k5_gather<<<dim3((k + 15) / 16, 2), 256, 0, stream>>>(embs, oidx, (float*)d_out, k);
}

// Round 11
// 48.096 us; speedup vs baseline: 3.7497x; 1.9843x over previous
//
#include <hip/hip_runtime.h>
#include <stdint.h>

// ---------------------------------------------------------------------------
// TopK: scores = (embs @ scorer)/sum(scorer) + mask; top-k rows; out = rows^T
// Ordering matches numpy/OpenBLAS sgemv_t fp32 bits exactly (verified
// R3/R5/R6/R8/R10, absmax=0): per row, 8 mod-8 fma chains (chain c sums
// elements c, c+8, ... ascending), reduced as ((L0+L4)+(L1+L5))+((L2+L6)+(L3+L7)),
// realized as 8 threads/row + shfl_xor pair-sums (bitwise-commutative adds).
// R11 = R8 pipeline with k1b+k2 merged into kHistFind using a SINGLE-POLLER
// wait. R10 lesson: 391 agent-scope acquire pollers = cross-XCD invalidate
// storm (65us); here exactly ONE thread polls an 8-RMW flag (R10's
// publish/consume recipe, HW-validated). Blocks 1-7 exit after publishing.
//   k1       : scores (verified body); block0 zeroes hdr.
//   kHistFind: 8 blocks x 1024 thr. Partial hists (verified k1b logic) ->
//              flag; block0 polls, reduces partials + suffix-scan (verified
//              R8-k2 logic) -> hdr[0]=B, hdr[1]=cumAbove.
//   k3/k4/k5 : unchanged verified bodies (compact / rank / gather-transpose).
// d_out: keys @ [0,400KB); partials @ [1.024MB,+256KB); k5 overwrites all.
// ws: hdr(1KB) ckey(16KB) cidx(16KB) oidx(8KB).
// ---------------------------------------------------------------------------

#define NBINS 8192   // 13-bit radix: sign + exp(8) + mantissa(4)
#define BIN_SHIFT 19
#define CAP 4096     // candidates: k + boundary bin (~600) << CAP
#define HPARTS 8

__device__ __forceinline__ uint32_t f2key(float f) {
  uint32_t b = __float_as_uint(f);
  return (b & 0x80000000u) ? ~b : (b | 0x80000000u);
}

// ---- kernel 1: 32 rows/block, 8 threads/row (one mod-8 chain each) --------
__global__ __launch_bounds__(256) void k1_scores(
    const float* __restrict__ embs, const float* __restrict__ mask,
    const float* __restrict__ scorer,
    uint32_t* __restrict__ keys, uint32_t* __restrict__ hdr, int N) {
  __shared__ float tile[32 * 132];
  __shared__ float sw[256];
  __shared__ float Ssh;
  int t = threadIdx.x;
  int r0 = blockIdx.x * 32;
  if (blockIdx.x == 0 && t < 16) hdr[t] = 0u;  // [0]=B [2]=cand ctr [8]=flag
  sw[t] = scorer[t];  // F == 256
  __syncthreads();
  if (t < 64) {
    double s = 0.0;
    for (int j = t; j < 256; j += 64) s += (double)sw[j];
#pragma unroll
    for (int off = 32; off >= 1; off >>= 1) s += __shfl_xor(s, off, 64);
    if (t == 0) Ssh = (float)s;  // f64 sum: order-independent at f32 grain
  }
  __syncthreads();
  float S = Ssh;
  int r = t >> 3, c = t & 7;
  float acc = 0.f;
  const float4* e4 = (const float4*)embs;
#pragma unroll
  for (int ch = 0; ch < 2; ++ch) {
    if (ch) __syncthreads();  // previous chunk's LDS reads complete
#pragma unroll
    for (int m = 0; m < 4; ++m) {      // 4*256 = 1024 f4 = 32 rows x 32 f4
      int flat = m * 256 + t;
      int rr = flat >> 5;              // 0..31
      int cc4 = flat & 31;             // 0..31
      int row = r0 + rr;
      float4 v = make_float4(0.f, 0.f, 0.f, 0.f);
      if (row < N) v = e4[(size_t)row * 64 + ch * 32 + cc4];  // 512B segs
      float* dst = &tile[rr * 132 + cc4 * 4];
      dst[0] = v.x; dst[1] = v.y; dst[2] = v.z; dst[3] = v.w;
    }
    __syncthreads();
#pragma unroll
    for (int sl = 0; sl < 16; ++sl) {  // ascending k within the chain
      acc = fmaf(tile[r * 132 + c + 8 * sl], sw[ch * 128 + c + 8 * sl], acc);
    }
  }
  // exact OpenBLAS bracket via commutative pair-sums (lanes stay in-row):
  float m1 = acc + __shfl_xor(acc, 4, 64);  // L_c + L_{c+4}
  float p1 = m1 + __shfl_xor(m1, 1, 64);    // (m0+m1) / (m2+m3)
  float dot = p1 + __shfl_xor(p1, 2, 64);   // ((m0+m1)+(m2+m3))
  int row = r0 + r;
  if (c == 0 && row < N) {
    float score = dot / S + mask[row];
    keys[row] = f2key(score);
  }
}

// ---- kernel HistFind: 8 partial hists; block0 (single poller) finds B -----
__global__ __launch_bounds__(1024) void kHistFind(
    const uint32_t* __restrict__ keys, uint32_t* __restrict__ partials,
    uint32_t* __restrict__ hdr, int N, int k) {
  __shared__ uint32_t h[2][NBINS];  // 64 KB
  __shared__ uint32_t wtot[16], wsuf[16];
  int t = threadIdx.x, bid = blockIdx.x;
  int lane = t & 63, wave = t >> 6;

  // --- phase A: build this block's partial hist (plain stores) ---
  for (int i = t; i < 2 * NBINS; i += 1024) ((uint32_t*)h)[i] = 0u;
  __syncthreads();
  int per = (N + HPARTS - 1) / HPARTS;
  int lo = bid * per;
  int hi = lo + per; if (hi > N) hi = N;
  int sub = (t >> 7) & 1;
  int n4 = (hi - lo) >> 2;
  const uint4* q4 = (const uint4*)(keys + lo);
  for (int i = t; i < n4; i += 1024) {
    uint4 v = q4[i];
    atomicAdd(&h[sub][v.x >> BIN_SHIFT], 1u);
    atomicAdd(&h[sub][v.y >> BIN_SHIFT], 1u);
    atomicAdd(&h[sub][v.z >> BIN_SHIFT], 1u);
    atomicAdd(&h[sub][v.w >> BIN_SHIFT], 1u);
  }
  for (int i = lo + (n4 << 2) + t; i < hi; i += 1024)
    atomicAdd(&h[sub][keys[i] >> BIN_SHIFT], 1u);
  __syncthreads();
  uint32_t* dst = partials + (size_t)bid * NBINS;
  for (int i = t; i < NBINS; i += 1024) dst[i] = h[0][i] + h[1][i];
  __syncthreads();
  if (t == 0) {
    __threadfence();  // publish partials (agent scope)
    __hip_atomic_fetch_add(&hdr[8], 1u, __ATOMIC_ACQ_REL, __HIP_MEMORY_SCOPE_AGENT);
  }
  if (bid != 0) return;

  // --- single poller: only block 0 thread 0 spins (R10 lesson) ---
  if (t == 0) {
    while (__hip_atomic_load(&hdr[8], __ATOMIC_ACQUIRE, __HIP_MEMORY_SCOPE_AGENT) < HPARTS)
      __builtin_amdgcn_s_sleep(8);
  }
  __syncthreads();

  // --- phase B: reduce 8 partials (8 bins/thread) + suffix scan (R8 k2) ---
  uint32_t rb[8];
#pragma unroll
  for (int j = 0; j < 8; ++j) rb[j] = 0u;
#pragma unroll
  for (int pp = 0; pp < HPARTS; ++pp) {
    const uint4* q = (const uint4*)(partials + (size_t)pp * NBINS) + t * 2;
    uint4 a = q[0], b2 = q[1];
    rb[0] += a.x;  rb[1] += a.y;  rb[2] += a.z;  rb[3] += a.w;
    rb[4] += b2.x; rb[5] += b2.y; rb[6] += b2.z; rb[7] += b2.w;
  }
  uint32_t p8 = rb[0] + rb[1] + rb[2] + rb[3] + rb[4] + rb[5] + rb[6] + rb[7];
  uint32_t x = p8;  // wave-internal inclusive suffix scan
#pragma unroll
  for (int off = 1; off < 64; off <<= 1) {
    uint32_t v = __shfl_down(x, off, 64);
    if (lane + off < 64) x += v;
  }
  if (lane == 0) wtot[wave] = x;
  __syncthreads();
  if (t < 16) {
    uint32_t y = wtot[t];
#pragma unroll
    for (int off = 1; off < 16; off <<= 1) {
      uint32_t v = __shfl_down(y, off, 64);
      if (t + off < 16) y += v;
    }
    wsuf[t] = y - wtot[t];  // sum of waves after t
  }
  __syncthreads();
  uint32_t St = x + wsuf[wave];  // count(bin >= 8t)
  uint32_t above = St - p8;      // count(bin >= 8(t+1))
  if (above < (uint32_t)k && St >= (uint32_t)k) {  // unique thread
    uint32_t cum = above;
#pragma unroll
    for (int jj = 7; jj >= 0; --jj) {
      if (cum + rb[jj] >= (uint32_t)k) { hdr[0] = (uint32_t)(t * 8 + jj); hdr[1] = cum; break; }
      cum += rb[jj];
    }
  }
}

// ---- kernel 3: compact candidates (bin >= B), block-aggregated atomic ------
__global__ __launch_bounds__(256) void k3_compact(
    const uint32_t* __restrict__ keys, const uint32_t* __restrict__ hdr,
    uint32_t* __restrict__ ckey, uint32_t* __restrict__ cidx,
    uint32_t* __restrict__ counter, int N) {
  __shared__ uint32_t wcnt[4];
  __shared__ uint32_t wbase[4];
  __shared__ uint32_t blkbase;
  int i = blockIdx.x * 256 + threadIdx.x;
  int wave = threadIdx.x >> 6, lane = threadIdx.x & 63;
  uint32_t B = hdr[0];
  bool pred = false;
  uint32_t key = 0;
  if (i < N) {
    key = keys[i];
    pred = (key >> BIN_SHIFT) >= B;
  }
  unsigned long long ball = __ballot(pred);
  uint32_t prefix = (uint32_t)__popcll(ball & ((1ull << lane) - 1ull));
  if (lane == 0) wcnt[wave] = (uint32_t)__popcll(ball);
  __syncthreads();
  if (threadIdx.x == 0) {
    uint32_t tot = wcnt[0] + wcnt[1] + wcnt[2] + wcnt[3];
    blkbase = tot ? atomicAdd(counter, tot) : 0u;
    wbase[0] = 0;
    wbase[1] = wcnt[0];
    wbase[2] = wcnt[0] + wcnt[1];
    wbase[3] = wcnt[0] + wcnt[1] + wcnt[2];
  }
  __syncthreads();
  if (pred) {
    uint32_t pos = blkbase + wbase[wave] + prefix;
    if (pos < CAP) { ckey[pos] = key; cidx[pos] = (uint32_t)i; }
  }
}

// ---- kernel 4: exact rank, 4 candidates/wave, 16/block --------------------
__global__ __launch_bounds__(256) void k4_rank(
    const uint32_t* __restrict__ ckey, const uint32_t* __restrict__ cidx,
    const uint32_t* __restrict__ hdr, uint32_t* __restrict__ oidx, int k) {
  __shared__ uint32_t lk[CAP];
  __shared__ uint32_t li[CAP];
  uint32_t C = hdr[2];
  if (C > CAP) C = CAP;
  uint32_t base = blockIdx.x * 16u;
  if (base >= C) return;
  for (uint32_t j = threadIdx.x; j < C; j += 256u) {
    lk[j] = ckey[j];
    li[j] = cidx[j];
  }
  __syncthreads();
  int wave = threadIdx.x >> 6, lane = threadIdx.x & 63;
  uint32_t g0 = base + wave * 4u;
  uint32_t mk[4], mi[4], cnt[4];
#pragma unroll
  for (int q = 0; q < 4; ++q) {
    uint32_t g = g0 + q;
    bool valid = g < C;
    mk[q] = valid ? lk[g] : 0u;
    mi[q] = valid ? li[g] : 0xFFFFFFFFu;
    cnt[q] = 0u;
  }
  for (uint32_t j = lane; j < C; j += 64u) {
    uint32_t kj = lk[j], ij = li[j];
#pragma unroll
    for (int q = 0; q < 4; ++q)
      cnt[q] += (kj > mk[q] || (kj == mk[q] && ij < mi[q])) ? 1u : 0u;
  }
#pragma unroll
  for (int q = 0; q < 4; ++q) {
#pragma unroll
    for (int off = 32; off >= 1; off >>= 1) cnt[q] += __shfl_xor(cnt[q], off, 64);
  }
  if (lane == 0) {
#pragma unroll
    for (int q = 0; q < 4; ++q) {
      uint32_t g = g0 + q;
      if (g < C && cnt[q] < (uint32_t)k) oidx[cnt[q]] = mi[q];
    }
  }
}

// ---- kernel 5: gather + transpose; 16 ranks x 128 feats per block ----------
__global__ __launch_bounds__(256) void k5_gather(
    const float* __restrict__ embs, const uint32_t* __restrict__ oidx,
    float* __restrict__ out, int k) {
  __shared__ float tile[16 * 132];
  __shared__ uint32_t sidx[16];
  int t = threadIdx.x;
  int r0 = blockIdx.x * 16;
  int fb = blockIdx.y * 128;
  if (t < 16) sidx[t] = (r0 + t < k) ? oidx[r0 + t] : 0u;
  __syncthreads();
  const float4* e4 = (const float4*)embs;
#pragma unroll
  for (int m = 0; m < 2; ++m) {      // 2*256 = 512 f4 = 16 rows x 32 f4
    int flat = m * 256 + t;
    int rr = flat >> 5;
    int cc4 = flat & 31;
    float4 v = e4[(size_t)sidx[rr] * 64 + (fb >> 2) + cc4];
    float* dst = &tile[rr * 132 + cc4 * 4];
    dst[0] = v.x; dst[1] = v.y; dst[2] = v.z; dst[3] = v.w;
  }
  __syncthreads();
  int fl = t >> 1;   // 0..127 local feature
  int rq = t & 1;    // which 8-rank group
  float v[8];
#pragma unroll
  for (int i = 0; i < 8; ++i) v[i] = tile[(rq * 8 + i) * 132 + fl];
  size_t obase = (size_t)(fb + fl) * k + r0 + rq * 8;
  if (((k & 3) == 0) && (r0 + rq * 8 + 7 < k)) {
    *(float4*)(out + obase) = make_float4(v[0], v[1], v[2], v[3]);
    *(float4*)(out + obase + 4) = make_float4(v[4], v[5], v[6], v[7]);
  } else {
#pragma unroll
    for (int i = 0; i < 8; ++i)
      if (r0 + rq * 8 + i < k) out[obase + i] = v[i];
  }
}

extern "C" void kernel_launch(void* const* d_in, const int* in_sizes, int n_in,
                              void* d_out, int out_size, void* d_ws, size_t ws_size,
                              hipStream_t stream) {
  const float* embs = (const float*)d_in[0];
  const float* mask = (const float*)d_in[1];
  const float* scorer = (const float*)d_in[2];
  int F = in_sizes[2];      // 256
  int N = in_sizes[0] / F;  // 100000
  int k = out_size / F;     // 2000

  // d_out scratch layout (overwritten by k5 at the end):
  //   keys     @ [0, N*4)                 = 400 KB
  //   partials @ [out_size/2 * 4, +256KB)
  uint32_t* keys = (uint32_t*)d_out;
  uint32_t* partials = (uint32_t*)d_out + (out_size / 2);

  char* ws = (char*)d_ws;
  uint32_t* hdr = (uint32_t*)ws;                 // 1KB: [0]=B [1]=cum [2]=C [8]=flag
  uint32_t* ckey = (uint32_t*)(ws + 1024);       // 16KB
  uint32_t* cidx = ckey + CAP;                   // 16KB
  uint32_t* oidx = cidx + CAP;                   // 8KB

  k1_scores<<<(N + 31) / 32, 256, 0, stream>>>(embs, mask, scorer, keys, hdr, N);
  kHistFind<<<HPARTS, 1024, 0, stream>>>(keys, partials, hdr, N, k);
  k3_compact<<<(N + 255) / 256, 256, 0, stream>>>(keys, hdr, ckey, cidx, &hdr[2], N);
  k4_rank<<<(CAP + 15) / 16, 256, 0, stream>>>(ckey, cidx, hdr, oidx, k);
  k5_gather<<<dim3((k + 15) / 16, 2), 256, 0, stream>>>(embs, oidx, (float*)d_out, k);
}